// Round 1
// baseline (873.961 us; speedup 1.0000x reference)
//
#include <hip/hip_runtime.h>

// Problem constants (fixed by the reference).
#define NGRID 262144      // N = 64^3 = 2^18
#define NNZ_C 1835008     // 7 * N
#define TP    260         // prep LDS row stride (floats); 260*4 ≡ 0 mod 16
#define NBKT  2048        // row buckets: row >> 7, 128 rows each

// Loss closed form:  loss = mean_b( Stt - 2a*C2 + a^2*C3 ),  a = Sty/C1
//   C1=<yp,yat>  C2=<yt,yat>  C3=<yat,yat>  Stt=<yt,yt>  Sty=<yt,yp>
// NEW (this round): yat is NEVER materialized in global memory. Edges are
// bucketed by row>>7; one block per bucket accumulates its 128x32 yat tile
// in LDS via ds_add_f32 and folds the five dot-products directly into p2.
// This removes the 1.83M coherent-point line-RMW atomics (the 198 us floor
// of the old k_scatter: ~1 lane-atomic/cycle/TCC-channel) and deletes k_post.

// ---------------------------------------------------------------------------
// K1: dual-family transpose (R7-green tile construct, unchanged) + zero the
// bucket histogram from block 0. No yat_t anymore.
//   family 0 (blk<1024):  yp(32,N) -> yp_t(N,32)
//   family 1 (blk>=1024): yt(32,N) -> yt_t(N,32)
// ---------------------------------------------------------------------------
__global__ __launch_bounds__(256) void k_prep(
        const float* __restrict__ yp, const float* __restrict__ yt,
        float* __restrict__ yp_t, float* __restrict__ yt_t,
        unsigned* __restrict__ counts) {
    __shared__ __align__(16) float T[32 * TP];
    const int tid = threadIdx.x;
    if (blockIdx.x == 0) {
        #pragma unroll
        for (int i = 0; i < 8; ++i) counts[i * 256 + tid] = 0u;
    }
    const int l = tid & 63, w = tid >> 6;
    const int fam = blockIdx.x >> 10;            // 0: yp, 1: yt
    const size_t n0 = (size_t)(blockIdx.x & 1023) * 256;
    const float* src = fam ? yt : yp;
    #pragma unroll
    for (int s = 0; s < 8; ++s) {
        const int b = s * 4 + w;                 // unique (s,w) -> 0..31
        const float4 a = *(const float4*)(src + (size_t)b * NGRID + n0 + 4 * l);
        *(float4*)(&T[b * TP + 4 * l]) = a;      // ds_write_b128, row b
    }
    __syncthreads();
    float4* dst4 = (float4*)((fam ? yt_t : yp_t) + n0 * 32);
    #pragma unroll
    for (int q = 0; q < 8; ++q) {
        const int f = q * 256 + tid;             // float4 index, 0..2047
        const int n = f >> 3;                    // 0..255 local n
        const int bb = 4 * (f & 7);              // base batch of this quad
        float4 v;
        v.x = T[(bb + 0) * TP + n];
        v.y = T[(bb + 1) * TP + n];
        v.z = T[(bb + 2) * TP + n];
        v.w = T[(bb + 3) * TP + n];
        dst4[f] = v;                             // coalesced 1 KB/wave
    }
}

// ---------------------------------------------------------------------------
// K2a: bucket histogram. 4 edges/thread via int4; atomics land on 64 hot L2
// lines (8 KB counter array) -> L2-resident atomic throughput, ~6 us.
// grid = NNZ/1024 = 1792.
// ---------------------------------------------------------------------------
__global__ __launch_bounds__(256) void k_hist(const int* __restrict__ rows,
                                              unsigned* __restrict__ counts) {
    const size_t i4 = (size_t)blockIdx.x * 256 + threadIdx.x;
    const int4 r = ((const int4*)rows)[i4];
    atomicAdd(&counts[(unsigned)r.x >> 7], 1u);
    atomicAdd(&counts[(unsigned)r.y >> 7], 1u);
    atomicAdd(&counts[(unsigned)r.z >> 7], 1u);
    atomicAdd(&counts[(unsigned)r.w >> 7], 1u);
}

// ---------------------------------------------------------------------------
// K2b: exclusive scan of the 2048 counts -> offs (bucket bases) + cursor
// (working copy for k_bucket). 1 block x 256, Hillis-Steele over 256
// per-thread sums of 8 counts each.
// ---------------------------------------------------------------------------
__global__ __launch_bounds__(256) void k_scan(
        const unsigned* __restrict__ counts,
        unsigned* __restrict__ offs, unsigned* __restrict__ cursor) {
    __shared__ unsigned ts[256];
    const int tid = threadIdx.x;
    unsigned c[8];
    unsigned s = 0;
    #pragma unroll
    for (int i = 0; i < 8; ++i) { c[i] = counts[tid * 8 + i]; s += c[i]; }
    ts[tid] = s;
    __syncthreads();
    for (int d = 1; d < 256; d <<= 1) {
        const unsigned v = (tid >= d) ? ts[tid - d] : 0u;
        __syncthreads();
        ts[tid] += v;
        __syncthreads();
    }
    unsigned base = (tid == 0) ? 0u : ts[tid - 1];
    #pragma unroll
    for (int i = 0; i < 8; ++i) {
        offs[tid * 8 + i] = base;
        cursor[tid * 8 + i] = base;
        base += c[i];
    }
}

// ---------------------------------------------------------------------------
// K2c: bucket scatter. 1 edge/thread, grid = NNZ/256 = 7168. Slot via
// atomicAdd on the bucket cursor (hot 8 KB in L2). Payload packs
// col (18b) | rlow (7b) into one u32 + the f32 value -> one 8 B store/edge
// (15 MB total vs the old 229 MB of line-RMWs).
// ---------------------------------------------------------------------------
__global__ __launch_bounds__(256) void k_bucket(
        const float* __restrict__ vals, const int* __restrict__ rows,
        const int* __restrict__ cols, unsigned* __restrict__ cursor,
        uint2* __restrict__ bkt) {
    const size_t e = (size_t)blockIdx.x * 256 + threadIdx.x;
    const unsigned r = (unsigned)rows[e];
    const unsigned c = (unsigned)cols[e];
    const float v = vals[e];
    const unsigned pos = atomicAdd(&cursor[r >> 7], 1u);
    bkt[pos] = make_uint2(c | ((r & 127u) << 18), __float_as_uint(v));
}

// ---------------------------------------------------------------------------
// K3: per-bucket accumulate + fused epilogue. Block g owns rows
// [128g, 128g+128). yat tile lives in LDS (128x32 f32 = 16 KB; 8 blocks/CU
// = full 32-wave occupancy). Edge loop: 8 lane-groups of 32 (one edge per
// group, b = lane&31 -> 32 distinct banks, conflict-free ds_add_f32),
// 4-deep unroll for gather MLP. Epilogue reads the tile + the block's
// contiguous 16 KB slices of yp_t/yt_t and emits the five per-batch partial
// sums straight into p2 (same 2048x160 shape as the old k_post output).
// ---------------------------------------------------------------------------
__global__ __launch_bounds__(256) void k_accum(
        const uint2* __restrict__ bkt, const unsigned* __restrict__ offs,
        const unsigned* __restrict__ counts,
        const float* __restrict__ yp_t, const float* __restrict__ yt_t,
        float* __restrict__ p2) {
    __shared__ float acc[128 * 32];              // 16 KB, reused as red[]
    const int tid = threadIdx.x;
    const int g = blockIdx.x;
    #pragma unroll
    for (int i = 0; i < 16; ++i) acc[i * 256 + tid] = 0.f;
    __syncthreads();
    const unsigned base = offs[g];
    const unsigned cnt = counts[g];
    const int b = tid & 31;                      // batch lane
    const uint2* eb = bkt + base;
    unsigned i = (unsigned)(tid >> 5);           // group id 0..7
    for (; i + 24 < cnt; i += 32) {
        const uint2 e0 = eb[i];
        const uint2 e1 = eb[i + 8];
        const uint2 e2 = eb[i + 16];
        const uint2 e3 = eb[i + 24];
        const float x0 = yp_t[(size_t)(e0.x & 0x3FFFFu) * 32 + b];
        const float x1 = yp_t[(size_t)(e1.x & 0x3FFFFu) * 32 + b];
        const float x2 = yp_t[(size_t)(e2.x & 0x3FFFFu) * 32 + b];
        const float x3 = yp_t[(size_t)(e3.x & 0x3FFFFu) * 32 + b];
        atomicAdd(&acc[(e0.x >> 18) * 32 + b], __uint_as_float(e0.y) * x0);
        atomicAdd(&acc[(e1.x >> 18) * 32 + b], __uint_as_float(e1.y) * x1);
        atomicAdd(&acc[(e2.x >> 18) * 32 + b], __uint_as_float(e2.y) * x2);
        atomicAdd(&acc[(e3.x >> 18) * 32 + b], __uint_as_float(e3.y) * x3);
    }
    for (; i < cnt; i += 8) {
        const uint2 e = eb[i];
        const float x = yp_t[(size_t)(e.x & 0x3FFFFu) * 32 + b];
        atomicAdd(&acc[(e.x >> 18) * 32 + b], __uint_as_float(e.y) * x);
    }
    __syncthreads();
    // Epilogue: idx = q*256+tid has idx&31 == tid&31 == b for all q.
    float c1 = 0.f, c2 = 0.f, c3 = 0.f, st = 0.f, sy = 0.f;
    const float* ypg = yp_t + (size_t)g * 4096;
    const float* ytg = yt_t + (size_t)g * 4096;
    #pragma unroll
    for (int q = 0; q < 16; ++q) {
        const int idx = q * 256 + tid;
        const float a = acc[idx];
        const float p = ypg[idx];
        const float t = ytg[idx];
        c1 = fmaf(p, a, c1); c2 = fmaf(t, a, c2); c3 = fmaf(a, a, c3);
        st = fmaf(t, t, st); sy = fmaf(t, p, sy);
    }
    __syncthreads();                             // acc reads done; reuse LDS
    float* red = acc;                            // 5*256 floats
    red[0 * 256 + tid] = c1;
    red[1 * 256 + tid] = c2;
    red[2 * 256 + tid] = c3;
    red[3 * 256 + tid] = st;
    red[4 * 256 + tid] = sy;
    __syncthreads();
    if (tid < 32) {                              // owner tid == b
        #pragma unroll
        for (int s = 0; s < 5; ++s) {
            float a2 = 0.f;
            #pragma unroll
            for (int j = 0; j < 8; ++j) a2 += red[s * 256 + tid + 32 * j];
            p2[(size_t)g * 160 + s * 32 + tid] = a2;
        }
    }
}

// ---------------------------------------------------------------------------
// K4a: stage-1 reduce. grid = 64 x 256. Block g sums p2 rows 32g..32g+31.
// ---------------------------------------------------------------------------
__global__ __launch_bounds__(256) void k_finish1(
        const float* __restrict__ p2, float* __restrict__ pr2) {
    const int tid = threadIdx.x, g = blockIdx.x;
    if (tid < 160) {
        float acc = 0.f;
        #pragma unroll
        for (int j = 0; j < 32; ++j) acc += p2[(size_t)(g * 32 + j) * 160 + tid];
        pr2[g * 160 + tid] = acc;
    }
}

// ---------------------------------------------------------------------------
// K4b: stage-2 reduce (64 rows) + closed-form loss. 1 block x 256.
// ---------------------------------------------------------------------------
__global__ __launch_bounds__(256) void k_finish2(
        const float* __restrict__ pr2, float* __restrict__ out) {
    __shared__ float tot[160];
    __shared__ float lb[32];
    const int tid = threadIdx.x;
    if (tid < 160) {
        float acc = 0.f;
        #pragma unroll
        for (int j = 0; j < 64; ++j) acc += pr2[j * 160 + tid];
        tot[tid] = acc;
    }
    __syncthreads();
    if (tid < 32) {
        const float c1 = tot[0 + tid];
        const float c2 = tot[32 + tid];
        const float c3 = tot[64 + tid];
        const float stt = tot[96 + tid];
        const float sty = tot[128 + tid];
        const float a = sty / c1;
        lb[tid] = fmaf(a * a, c3, fmaf(-2.f * a, c2, stt));
    }
    __syncthreads();
    if (tid == 0) {
        float s = 0.f;
        #pragma unroll
        for (int i = 0; i < 32; ++i) s += lb[i];
        out[0] = s * (1.0f / 32.0f);
    }
}

// ===========================================================================
extern "C" void kernel_launch(void* const* d_in, const int* in_sizes, int n_in,
                              void* d_out, int out_size, void* d_ws, size_t ws_size,
                              hipStream_t stream) {
    const float* yp = (const float*)d_in[0];   // y_pred (32, N)
    const float* yt = (const float*)d_in[1];   // y_true (32, N)
    const float* Av = (const float*)d_in[2];   // A_vals (NNZ)
    const int*   Ar = (const int*)d_in[3];     // A_rows (NNZ)
    const int*   Ac = (const int*)d_in[4];     // A_cols (NNZ)
    float* out = (float*)d_out;

    // Workspace: yp_t 32MB + yt_t 32MB + buckets 14.7MB + 3x8KB ctrl
    // + p2 1.3MB + pr2 40KB ≈ 83.2 MB. The previous (passing) kernel used
    // 98.7 MB, so this size is proven available.
    float*    ws     = (float*)d_ws;
    float*    yp_t   = ws;                                   // N*32
    float*    yt_t   = yp_t + (size_t)NGRID * 32;            // N*32
    uint2*    bkt    = (uint2*)(yt_t + (size_t)NGRID * 32);  // NNZ uint2
    unsigned* counts = (unsigned*)(bkt + NNZ_C);             // 2048
    unsigned* offs   = counts + NBKT;                        // 2048
    unsigned* cursor = offs + NBKT;                          // 2048
    float*    p2     = (float*)(cursor + NBKT);              // 2048*160
    float*    pr2    = p2 + 2048 * 160;                      // 64*160

    k_prep<<<2048, 256, 0, stream>>>(yp, yt, yp_t, yt_t, counts);
    k_hist<<<NNZ_C / 1024, 256, 0, stream>>>(Ar, counts);
    k_scan<<<1, 256, 0, stream>>>(counts, offs, cursor);
    k_bucket<<<NNZ_C / 256, 256, 0, stream>>>(Av, Ar, Ac, cursor, bkt);
    k_accum<<<NBKT, 256, 0, stream>>>(bkt, offs, counts, yp_t, yt_t, p2);
    k_finish1<<<64, 256, 0, stream>>>(p2, pr2);
    k_finish2<<<1, 256, 0, stream>>>(pr2, out);
}

// Round 2
// 549.971 us; speedup vs baseline: 1.5891x; 1.5891x over previous
//
#include <hip/hip_runtime.h>

// Problem constants (fixed by the reference).
#define NGRID 262144      // N = 64^3 = 2^18
#define NNZ_C 1835008     // 7 * N
#define TP    260         // prep LDS row stride (floats); 260*4 ≡ 0 mod 16
#define NBKT  2048        // row buckets: row >> 7, 128 rows each
#define BCAP  1280        // fixed bucket capacity (mean 896, 12.8 sigma)

// Loss closed form:  loss = mean_b( Stt - 2a*C2 + a^2*C3 ),  a = Sty/C1
//   C1=<yp,yat>  C2=<yt,yat>  C3=<yat,yat>  Stt=<yt,yt>  Sty=<yt,yp>
// Scheme: edges bucketed by row>>7 (fixed-capacity, no hist/scan); one
// block per bucket accumulates its 128x32 yat tile in LDS and folds the
// five dot products into p2. R1 post-mortem: bucket accum was LATENCY
// bound (4 gathers in flight/wave, 478 GB/s). This round: 8-lanes-per-edge
// float4 gather => 64 lines in flight per wave, swizzled LDS banks.

// ---------------------------------------------------------------------------
// K1: dual-family transpose (R7-green tile construct) + block 0 zeroes the
// padded bucket cursors (one counter per 64B line).
// ---------------------------------------------------------------------------
__global__ __launch_bounds__(256) void k_prep(
        const float* __restrict__ yp, const float* __restrict__ yt,
        float* __restrict__ yp_t, float* __restrict__ yt_t,
        unsigned* __restrict__ cursor) {
    __shared__ __align__(16) float T[32 * TP];
    const int tid = threadIdx.x;
    if (blockIdx.x == 0) {
        #pragma unroll
        for (int i = 0; i < 8; ++i) cursor[(i * 256 + tid) * 16] = 0u;
    }
    const int l = tid & 63, w = tid >> 6;
    const int fam = blockIdx.x >> 10;            // 0: yp, 1: yt
    const size_t n0 = (size_t)(blockIdx.x & 1023) * 256;
    const float* src = fam ? yt : yp;
    #pragma unroll
    for (int s = 0; s < 8; ++s) {
        const int b = s * 4 + w;                 // unique (s,w) -> 0..31
        const float4 a = *(const float4*)(src + (size_t)b * NGRID + n0 + 4 * l);
        *(float4*)(&T[b * TP + 4 * l]) = a;      // ds_write_b128, row b
    }
    __syncthreads();
    float4* dst4 = (float4*)((fam ? yt_t : yp_t) + n0 * 32);
    #pragma unroll
    for (int q = 0; q < 8; ++q) {
        const int f = q * 256 + tid;             // float4 index, 0..2047
        const int n = f >> 3;                    // 0..255 local n
        const int bb = 4 * (f & 7);              // base batch of this quad
        float4 v;
        v.x = T[(bb + 0) * TP + n];
        v.y = T[(bb + 1) * TP + n];
        v.z = T[(bb + 2) * TP + n];
        v.w = T[(bb + 3) * TP + n];
        dst4[f] = v;                             // coalesced 1 KB/wave
    }
}

// ---------------------------------------------------------------------------
// K2: bucket scatter, fixed capacity. 4 edges/thread via int4/float4.
// Cursor counters are line-padded (stride 16 u32) -> atomics parallel
// across all TCC channels. Payload: col(18b)|rlow(7b) + f32 val = 8 B/edge.
// grid = NNZ/1024 = 1792.
// ---------------------------------------------------------------------------
__global__ __launch_bounds__(256) void k_bucket(
        const float* __restrict__ vals, const int* __restrict__ rows,
        const int* __restrict__ cols, unsigned* __restrict__ cursor,
        uint2* __restrict__ bkt) {
    const size_t t = (size_t)blockIdx.x * 256 + threadIdx.x;
    const int4 r4 = ((const int4*)rows)[t];
    const int4 c4 = ((const int4*)cols)[t];
    const float4 v4 = ((const float4*)vals)[t];
    const unsigned ru[4] = {(unsigned)r4.x, (unsigned)r4.y,
                            (unsigned)r4.z, (unsigned)r4.w};
    const unsigned cu[4] = {(unsigned)c4.x, (unsigned)c4.y,
                            (unsigned)c4.z, (unsigned)c4.w};
    const float vu[4] = {v4.x, v4.y, v4.z, v4.w};
    #pragma unroll
    for (int k = 0; k < 4; ++k) {
        const unsigned g = ru[k] >> 7;
        const unsigned pos = atomicAdd(&cursor[g * 16], 1u);
        if (pos < BCAP)                          // 12.8-sigma guard
            bkt[(size_t)g * BCAP + pos] =
                make_uint2(cu[k] | ((ru[k] & 127u) << 18),
                           __float_as_uint(vu[k]));
    }
}

// ---------------------------------------------------------------------------
// K3: per-bucket accumulate + fused epilogue. Block g owns rows
// [128g, 128g+128); 16 KB LDS tile. Edge layout: slot = tid>>3 (32 edges
// per block-step), q = tid&7 (float4 of the 128 B yp_t row). One gather
// instruction covers 8 edges (16 lines); 4-deep unroll + next-step bkt
// prefetch => ~64 lines in flight per wave. LDS adds swizzled by
// b -> (b+row)&31 to spread banks.
// ---------------------------------------------------------------------------
__global__ __launch_bounds__(256) void k_accum(
        const uint2* __restrict__ bkt, const unsigned* __restrict__ cursor,
        const float* __restrict__ yp_t, const float* __restrict__ yt_t,
        float* __restrict__ p2) {
    __shared__ float acc[128 * 32];              // 16 KB, reused as red[]
    const int tid = threadIdx.x;
    const int g = blockIdx.x;
    float4* a4 = (float4*)acc;
    #pragma unroll
    for (int i = 0; i < 4; ++i)
        a4[i * 256 + tid] = make_float4(0.f, 0.f, 0.f, 0.f);
    __syncthreads();
    unsigned cnt = cursor[(size_t)g * 16];
    if (cnt > BCAP) cnt = BCAP;
    const uint2* eb = bkt + (size_t)g * BCAP;
    const float4* yp4 = (const float4*)yp_t;
    const int s = tid >> 3;                      // edge slot 0..31
    const int q = tid & 7;                       // float4 within row
    const unsigned nit = cnt >> 7;               // 128-edge iterations
    uint2 E[4];
    if (nit) {
        #pragma unroll
        for (int u = 0; u < 4; ++u) E[u] = eb[s + 32 * u];
        for (unsigned it = 0; it < nit; ++it) {
            float4 X[4];
            #pragma unroll
            for (int u = 0; u < 4; ++u)
                X[u] = yp4[(size_t)(E[u].x & 0x3FFFFu) * 8 + q];
            uint2 En[4] = {E[0], E[1], E[2], E[3]};
            if (it + 1 < nit) {
                const unsigned nb = (it + 1) * 128;
                #pragma unroll
                for (int u = 0; u < 4; ++u) En[u] = eb[nb + s + 32 * u];
            }
            #pragma unroll
            for (int u = 0; u < 4; ++u) {
                const unsigned rl = E[u].x >> 18;
                const float v = __uint_as_float(E[u].y);
                const float* x = (const float*)&X[u];
                #pragma unroll
                for (int k = 0; k < 4; ++k) {
                    const int b = 4 * q + k;
                    atomicAdd(&acc[rl * 32 + ((b + rl) & 31)], v * x[k]);
                }
            }
            #pragma unroll
            for (int u = 0; u < 4; ++u) E[u] = En[u];
        }
    }
    for (unsigned i = nit * 128 + s; i < cnt; i += 32) {   // tail
        const uint2 e = eb[i];
        const float4 X = yp4[(size_t)(e.x & 0x3FFFFu) * 8 + q];
        const unsigned rl = e.x >> 18;
        const float v = __uint_as_float(e.y);
        const float* x = (const float*)&X;
        #pragma unroll
        for (int k = 0; k < 4; ++k) {
            const int b = 4 * q + k;
            atomicAdd(&acc[rl * 32 + ((b + rl) & 31)], v * x[k]);
        }
    }
    __syncthreads();
    // Epilogue: idx&31 == tid&31 == batch for all q2; de-swizzle acc.
    float c1 = 0.f, c2 = 0.f, c3 = 0.f, st = 0.f, sy = 0.f;
    const float* ypg = yp_t + (size_t)g * 4096;
    const float* ytg = yt_t + (size_t)g * 4096;
    #pragma unroll
    for (int q2 = 0; q2 < 16; ++q2) {
        const int idx = q2 * 256 + tid;
        const int n = idx >> 5, b0 = idx & 31;
        const float a = acc[n * 32 + ((b0 + n) & 31)];
        const float p = ypg[idx];
        const float t = ytg[idx];
        c1 = fmaf(p, a, c1); c2 = fmaf(t, a, c2); c3 = fmaf(a, a, c3);
        st = fmaf(t, t, st); sy = fmaf(t, p, sy);
    }
    __syncthreads();                             // acc reads done; reuse LDS
    float* red = acc;                            // 5*256 floats
    red[0 * 256 + tid] = c1;
    red[1 * 256 + tid] = c2;
    red[2 * 256 + tid] = c3;
    red[3 * 256 + tid] = st;
    red[4 * 256 + tid] = sy;
    __syncthreads();
    if (tid < 32) {                              // owner tid == b
        #pragma unroll
        for (int sc = 0; sc < 5; ++sc) {
            float a2 = 0.f;
            #pragma unroll
            for (int j = 0; j < 8; ++j) a2 += red[sc * 256 + tid + 32 * j];
            p2[(size_t)g * 160 + sc * 32 + tid] = a2;
        }
    }
}

// ---------------------------------------------------------------------------
// K4a: stage-1 reduce. grid = 64 x 256. Block g sums p2 rows 32g..32g+31.
// ---------------------------------------------------------------------------
__global__ __launch_bounds__(256) void k_finish1(
        const float* __restrict__ p2, float* __restrict__ pr2) {
    const int tid = threadIdx.x, g = blockIdx.x;
    if (tid < 160) {
        float acc = 0.f;
        #pragma unroll
        for (int j = 0; j < 32; ++j) acc += p2[(size_t)(g * 32 + j) * 160 + tid];
        pr2[g * 160 + tid] = acc;
    }
}

// ---------------------------------------------------------------------------
// K4b: stage-2 reduce (64 rows) + closed-form loss. 1 block x 256.
// ---------------------------------------------------------------------------
__global__ __launch_bounds__(256) void k_finish2(
        const float* __restrict__ pr2, float* __restrict__ out) {
    __shared__ float tot[160];
    __shared__ float lb[32];
    const int tid = threadIdx.x;
    if (tid < 160) {
        float acc = 0.f;
        #pragma unroll
        for (int j = 0; j < 64; ++j) acc += pr2[j * 160 + tid];
        tot[tid] = acc;
    }
    __syncthreads();
    if (tid < 32) {
        const float c1 = tot[0 + tid];
        const float c2 = tot[32 + tid];
        const float c3 = tot[64 + tid];
        const float stt = tot[96 + tid];
        const float sty = tot[128 + tid];
        const float a = sty / c1;
        lb[tid] = fmaf(a * a, c3, fmaf(-2.f * a, c2, stt));
    }
    __syncthreads();
    if (tid == 0) {
        float s = 0.f;
        #pragma unroll
        for (int i = 0; i < 32; ++i) s += lb[i];
        out[0] = s * (1.0f / 32.0f);
    }
}

// ===========================================================================
extern "C" void kernel_launch(void* const* d_in, const int* in_sizes, int n_in,
                              void* d_out, int out_size, void* d_ws, size_t ws_size,
                              hipStream_t stream) {
    const float* yp = (const float*)d_in[0];   // y_pred (32, N)
    const float* yt = (const float*)d_in[1];   // y_true (32, N)
    const float* Av = (const float*)d_in[2];   // A_vals (NNZ)
    const int*   Ar = (const int*)d_in[3];     // A_rows (NNZ)
    const int*   Ac = (const int*)d_in[4];     // A_cols (NNZ)
    float* out = (float*)d_out;

    // Workspace: yp_t 33.6MB + yt_t 33.6MB + bkt 21.0MB + cursor 128KB
    // + p2 1.3MB + pr2 40KB ≈ 89.7 MB  (< 98.7 MB proven by the round-0
    // passing kernel).
    float*    ws     = (float*)d_ws;
    float*    yp_t   = ws;                                   // N*32
    float*    yt_t   = yp_t + (size_t)NGRID * 32;            // N*32
    uint2*    bkt    = (uint2*)(yt_t + (size_t)NGRID * 32);  // NBKT*BCAP
    unsigned* cursor = (unsigned*)(bkt + (size_t)NBKT * BCAP); // 2048*16
    float*    p2     = (float*)(cursor + NBKT * 16);         // 2048*160
    float*    pr2    = p2 + 2048 * 160;                      // 64*160

    k_prep<<<2048, 256, 0, stream>>>(yp, yt, yp_t, yt_t, cursor);
    k_bucket<<<NNZ_C / 1024, 256, 0, stream>>>(Av, Ar, Ac, cursor, bkt);
    k_accum<<<NBKT, 256, 0, stream>>>(bkt, cursor, yp_t, yt_t, p2);
    k_finish1<<<64, 256, 0, stream>>>(p2, pr2);
    k_finish2<<<1, 256, 0, stream>>>(pr2, out);
}

// Round 3
// 323.365 us; speedup vs baseline: 2.7027x; 1.7008x over previous
//
#include <hip/hip_runtime.h>

// Problem constants (fixed by the reference).
#define NGRID 262144      // N = 64^3 = 2^18
#define NNZ_C 1835008     // 7 * N
#define TP    260         // prep LDS row stride (floats); 260*4 ≡ 0 mod 16
#define NS    256         // k_post n-slice per block
#define TPAD  260         // k_post LDS row stride (floats), 16B-aligned rows

// Loss closed form:  loss = mean_b( Stt - 2a*C2 + a^2*C3 ),  a = Sty/C1
//   C1=<yp,yat>  C2=<yt,yat>  C3=<yat,yat>  Stt=<yt,yt>  Sty=<yt,yp>
// R2 post-mortem: bucketed-LDS accumulate pinned at 305us regardless of
// gather structure (failed twice) -> reverted to the proven round-0
// scatter (198us, atomic-unit floor). This round removes yt_t entirely:
// k_post reads yt/yp in ORIGINAL (32,N) layout (coalesced per-batch runs)
// and LDS-transposes only the yat tile. k_prep halves to yp-only.
// p2 is 1024 x 160: slot*32+b; slots 0=C1 1=C2 2=C3 3=Stt 4=Sty.

// ---------------------------------------------------------------------------
// K1: yp transpose (R7-green tile construct, fam-0 path verbatim) + zero
// yat_t. grid = 1024 x 256.
// ---------------------------------------------------------------------------
__global__ __launch_bounds__(256) void k_prep(
        const float* __restrict__ yp, float* __restrict__ yp_t,
        float* __restrict__ yat_t) {
    __shared__ __align__(16) float T[32 * TP];
    const int tid = threadIdx.x;
    const int l = tid & 63, w = tid >> 6;
    const size_t n0 = (size_t)blockIdx.x * 256;
    #pragma unroll
    for (int s = 0; s < 8; ++s) {
        const int b = s * 4 + w;                 // unique (s,w) -> 0..31
        const float4 a = *(const float4*)(yp + (size_t)b * NGRID + n0 + 4 * l);
        *(float4*)(&T[b * TP + 4 * l]) = a;      // ds_write_b128, row b
    }
    __syncthreads();
    float4* dst4 = (float4*)(yp_t + n0 * 32);
    float4* yat4 = (float4*)(yat_t + n0 * 32);
    #pragma unroll
    for (int q = 0; q < 8; ++q) {
        const int f = q * 256 + tid;             // float4 index, 0..2047
        const int n = f >> 3;                    // 0..255 local n
        const int bb = 4 * (f & 7);              // base batch of this quad
        float4 v;
        v.x = T[(bb + 0) * TP + n];
        v.y = T[(bb + 1) * TP + n];
        v.z = T[(bb + 2) * TP + n];
        v.w = T[(bb + 3) * TP + n];
        dst4[f] = v;                             // coalesced 1 KB/wave
        yat4[f] = make_float4(0.f, 0.f, 0.f, 0.f);
    }
}

// ---------------------------------------------------------------------------
// K2: COO scatter — round-0 verbatim (proven ~198 us; atomic-unit floor at
// one full-line RMW per edge). thread -> (e=tid>>5, b=tid&31).
// grid = NNZ*32/256 = 229376 blocks.
// ---------------------------------------------------------------------------
__global__ void k_scatter(const float* __restrict__ vals,
                          const int* __restrict__ rows,
                          const int* __restrict__ cols,
                          const float* __restrict__ yp_t,
                          float* __restrict__ yat_t) {
    const size_t tid = (size_t)blockIdx.x * blockDim.x + threadIdx.x;
    const int b = (int)(tid & 31);
    const size_t e = tid >> 5;
    const float v = vals[e];
    const int r = rows[e];
    const int c = cols[e];
    const float x = yp_t[(size_t)c * 32 + b];
    atomicAdd(&yat_t[(size_t)r * 32 + b], v * x);
}

// ---------------------------------------------------------------------------
// K3: post-pass, mixed-layout. Block g owns n-slice [256g, 256g+256).
//   Phase A: load yat tile (256 x 32, coalesced float4) -> LDS transposed
//            T[b][n], row stride TPAD=260 (rows 16B-aligned; ~2-way write
//            aliasing only).
//   Phase B: thread (b=tid>>3, j=tid&7): 8 steps of float4 over n; reads
//            yt[b]/yp[b] original layout (8 lanes x 16B = 128 B contiguous
//            per batch group) + ds_read_b128 from T. All five scalars in
//            registers; shfl-reduce over the 8 lanes per b.
// ---------------------------------------------------------------------------
__global__ __launch_bounds__(256) void k_post(
        const float* __restrict__ yat_t, const float* __restrict__ yp,
        const float* __restrict__ yt, float* __restrict__ p2) {
    __shared__ __align__(16) float T[32 * TPAD];     // 33.3 KB
    const int tid = threadIdx.x;
    const int g = blockIdx.x;                    // 0..1023
    const size_t n0 = (size_t)g * NS;
    const float4* yat4 = (const float4*)(yat_t + n0 * 32);
    #pragma unroll
    for (int q = 0; q < 8; ++q) {
        const int f = q * 256 + tid;             // 0..2047
        const int n = f >> 3;                    // 0..255
        const int b0 = 4 * (f & 7);
        const float4 v = yat4[f];
        T[(b0 + 0) * TPAD + n] = v.x;
        T[(b0 + 1) * TPAD + n] = v.y;
        T[(b0 + 2) * TPAD + n] = v.z;
        T[(b0 + 3) * TPAD + n] = v.w;
    }
    __syncthreads();
    const int b = tid >> 3, j = tid & 7;
    const float* ytb = yt + (size_t)b * NGRID + n0;
    const float* ypb = yp + (size_t)b * NGRID + n0;
    const float* Tb = &T[b * TPAD];
    float c1 = 0.f, c2 = 0.f, c3 = 0.f, st = 0.f, sy = 0.f;
    #pragma unroll
    for (int s = 0; s < NS / 32; ++s) {          // 8 steps
        const int n = 4 * j + 32 * s;
        const float4 a = *(const float4*)(Tb + n);     // ds_read_b128
        const float4 t = *(const float4*)(ytb + n);
        const float4 p = *(const float4*)(ypb + n);
        c1 = fmaf(p.x, a.x, c1); c2 = fmaf(t.x, a.x, c2);
        c3 = fmaf(a.x, a.x, c3); st = fmaf(t.x, t.x, st);
        sy = fmaf(t.x, p.x, sy);
        c1 = fmaf(p.y, a.y, c1); c2 = fmaf(t.y, a.y, c2);
        c3 = fmaf(a.y, a.y, c3); st = fmaf(t.y, t.y, st);
        sy = fmaf(t.y, p.y, sy);
        c1 = fmaf(p.z, a.z, c1); c2 = fmaf(t.z, a.z, c2);
        c3 = fmaf(a.z, a.z, c3); st = fmaf(t.z, t.z, st);
        sy = fmaf(t.z, p.z, sy);
        c1 = fmaf(p.w, a.w, c1); c2 = fmaf(t.w, a.w, c2);
        c3 = fmaf(a.w, a.w, c3); st = fmaf(t.w, t.w, st);
        sy = fmaf(t.w, p.w, sy);
    }
    #pragma unroll
    for (int d = 4; d; d >>= 1) {                // reduce 8 lanes per b
        c1 += __shfl_down(c1, d, 8);
        c2 += __shfl_down(c2, d, 8);
        c3 += __shfl_down(c3, d, 8);
        st += __shfl_down(st, d, 8);
        sy += __shfl_down(sy, d, 8);
    }
    if (j == 0) {
        float* row = p2 + (size_t)g * 160;
        row[0 * 32 + b] = c1;
        row[1 * 32 + b] = c2;
        row[2 * 32 + b] = c3;
        row[3 * 32 + b] = st;
        row[4 * 32 + b] = sy;
    }
}

// ---------------------------------------------------------------------------
// K4a: stage-1 reduce. grid = 32 x 256. Block g sums p2 rows 32g..32g+31.
// ---------------------------------------------------------------------------
__global__ __launch_bounds__(256) void k_finish1(
        const float* __restrict__ p2, float* __restrict__ pr2) {
    const int tid = threadIdx.x, g = blockIdx.x;
    if (tid < 160) {
        float acc = 0.f;
        #pragma unroll
        for (int j = 0; j < 32; ++j) acc += p2[(size_t)(g * 32 + j) * 160 + tid];
        pr2[g * 160 + tid] = acc;
    }
}

// ---------------------------------------------------------------------------
// K4b: stage-2 reduce (32 rows) + closed-form loss. 1 block x 256.
// ---------------------------------------------------------------------------
__global__ __launch_bounds__(256) void k_finish2(
        const float* __restrict__ pr2, float* __restrict__ out) {
    __shared__ float tot[160];
    __shared__ float lb[32];
    const int tid = threadIdx.x;
    if (tid < 160) {
        float acc = 0.f;
        #pragma unroll
        for (int j = 0; j < 32; ++j) acc += pr2[j * 160 + tid];
        tot[tid] = acc;
    }
    __syncthreads();
    if (tid < 32) {
        const float c1 = tot[0 + tid];
        const float c2 = tot[32 + tid];
        const float c3 = tot[64 + tid];
        const float stt = tot[96 + tid];
        const float sty = tot[128 + tid];
        const float a = sty / c1;
        lb[tid] = fmaf(a * a, c3, fmaf(-2.f * a, c2, stt));
    }
    __syncthreads();
    if (tid == 0) {
        float s = 0.f;
        #pragma unroll
        for (int i = 0; i < 32; ++i) s += lb[i];
        out[0] = s * (1.0f / 32.0f);
    }
}

// ===========================================================================
extern "C" void kernel_launch(void* const* d_in, const int* in_sizes, int n_in,
                              void* d_out, int out_size, void* d_ws, size_t ws_size,
                              hipStream_t stream) {
    const float* yp = (const float*)d_in[0];   // y_pred (32, N)
    const float* yt = (const float*)d_in[1];   // y_true (32, N)
    const float* Av = (const float*)d_in[2];   // A_vals (NNZ)
    const int*   Ar = (const int*)d_in[3];     // A_rows (NNZ)
    const int*   Ac = (const int*)d_in[4];     // A_cols (NNZ)
    float* out = (float*)d_out;

    // Workspace: yp_t 33.6MB + yat_t 33.6MB + p2 640KB + pr2 20KB ≈ 68 MB
    // (round-0 proved >= 82.5 MB available; yt_t is gone).
    float* ws    = (float*)d_ws;
    float* yp_t  = ws;                              // N*32
    float* yat_t = yp_t + (size_t)NGRID * 32;       // N*32
    float* p2    = yat_t + (size_t)NGRID * 32;      // 1024*160
    float* pr2   = p2 + 1024 * 160;                 // 32*160

    k_prep<<<1024, 256, 0, stream>>>(yp, yp_t, yat_t);
    k_scatter<<<(NNZ_C * 32) / 256, 256, 0, stream>>>(Av, Ar, Ac, yp_t, yat_t);
    k_post<<<1024, 256, 0, stream>>>(yat_t, yp, yt, p2);
    k_finish1<<<32, 256, 0, stream>>>(p2, pr2);
    k_finish2<<<1, 256, 0, stream>>>(pr2, out);
}

// Round 4
// 298.413 us; speedup vs baseline: 2.9287x; 1.0836x over previous
//
#include <hip/hip_runtime.h>

// Problem constants (fixed by the reference).
#define NGRID 262144      // N = 64^3 = 2^18
#define NNZ_C 1835008     // 7 * N
#define TP    260         // prep LDS row stride (floats); 260*4 ≡ 0 mod 16
#define NS    256         // k_post n-slice per block
#define TPAD  260         // k_post LDS row stride (floats), 16B-aligned rows

// Fixed-point scale for packed-pair atomic accumulation of yat.
// |value| bound before low-lane overflow: 2^31/2^19 = 4096 (typ |sum| < 50).
#define FPSCALE   524288.0f          // 2^19
#define FPINV     (1.0f / 524288.0f)

// Loss closed form:  loss = mean_b( Stt - 2a*C2 + a^2*C3 ),  a = Sty/C1
//   C1=<yp,yat>  C2=<yt,yat>  C3=<yat,yat>  Stt=<yt,yt>  Sty=<yt,yp>
// R3 structure (323us) kept verbatim EXCEPT: yat accumulation now packs
// TWO batch lanes into ONE u64 atomic (exact int64 fixed-point identity:
// pack = (i64)hi<<32 + (i64)lo, u64 sum == sum of packs). Scatter rate was
// measured op-limited (1 lane-atomic/cy/TCC-channel, 296G/s; BW only 1.2
// TB/s) -> halving op count should halve the 196us scatter.

// ---------------------------------------------------------------------------
// K1: yp transpose (R7-green tile construct) + zero yat (bytes are bytes;
// zero fixed-point == zero). grid = 1024 x 256.
// ---------------------------------------------------------------------------
__global__ __launch_bounds__(256) void k_prep(
        const float* __restrict__ yp, float* __restrict__ yp_t,
        float* __restrict__ yat_t) {
    __shared__ __align__(16) float T[32 * TP];
    const int tid = threadIdx.x;
    const int l = tid & 63, w = tid >> 6;
    const size_t n0 = (size_t)blockIdx.x * 256;
    #pragma unroll
    for (int s = 0; s < 8; ++s) {
        const int b = s * 4 + w;                 // unique (s,w) -> 0..31
        const float4 a = *(const float4*)(yp + (size_t)b * NGRID + n0 + 4 * l);
        *(float4*)(&T[b * TP + 4 * l]) = a;      // ds_write_b128, row b
    }
    __syncthreads();
    float4* dst4 = (float4*)(yp_t + n0 * 32);
    float4* yat4 = (float4*)(yat_t + n0 * 32);
    #pragma unroll
    for (int q = 0; q < 8; ++q) {
        const int f = q * 256 + tid;             // float4 index, 0..2047
        const int n = f >> 3;                    // 0..255 local n
        const int bb = 4 * (f & 7);              // base batch of this quad
        float4 v;
        v.x = T[(bb + 0) * TP + n];
        v.y = T[(bb + 1) * TP + n];
        v.z = T[(bb + 2) * TP + n];
        v.w = T[(bb + 3) * TP + n];
        dst4[f] = v;                             // coalesced 1 KB/wave
        yat4[f] = make_float4(0.f, 0.f, 0.f, 0.f);
    }
}

// ---------------------------------------------------------------------------
// K2: COO scatter, packed pairs. thread -> (e=tid>>4, b2=tid&15); each
// thread handles batches (2*b2, 2*b2+1): float2 gather from yp_t row c
// (16 lanes x 8B = same 128B line as before), fixed-point convert, ONE
// u64 atomic per pair. 29.4M lane-atomics (was 58.7M).
// grid = NNZ*16/256 = 114688 blocks.
// ---------------------------------------------------------------------------
__global__ void k_scatter(const float* __restrict__ vals,
                          const int* __restrict__ rows,
                          const int* __restrict__ cols,
                          const float* __restrict__ yp_t,
                          unsigned long long* __restrict__ yat64) {
    const size_t tid = (size_t)blockIdx.x * blockDim.x + threadIdx.x;
    const int b2 = (int)(tid & 15);
    const size_t e = tid >> 4;
    const float v = vals[e];
    const int r = rows[e];
    const int c = cols[e];
    const float2 x2 = *(const float2*)(yp_t + (size_t)c * 32 + 2 * b2);
    const long long i0 = (long long)__float2int_rn(v * x2.x * FPSCALE);
    const long long i1 = (long long)__float2int_rn(v * x2.y * FPSCALE);
    const unsigned long long pk = (unsigned long long)((i1 << 32) + i0);
    atomicAdd(&yat64[(size_t)r * 16 + b2], pk);
}

// ---------------------------------------------------------------------------
// K3: post-pass, mixed-layout (R3 structure). Block g owns n-slice
// [256g, 256g+256).
//   Phase A: load packed yat tile (256 x 16 u64, coalesced ulonglong2),
//            unpack exact int64 identity -> f32, store LDS transposed
//            T[b][n], row stride TPAD=260.
//   Phase B: thread (b=tid>>3, j=tid&7): 8 float4 steps over n; yt/yp in
//            ORIGINAL (32,N) layout + ds_read_b128 from T; shfl-reduce
//            the 8 lanes per batch.
// ---------------------------------------------------------------------------
__global__ __launch_bounds__(256) void k_post(
        const unsigned long long* __restrict__ yat64,
        const float* __restrict__ yp, const float* __restrict__ yt,
        float* __restrict__ p2) {
    __shared__ __align__(16) float T[32 * TPAD];     // 33.3 KB
    const int tid = threadIdx.x;
    const int g = blockIdx.x;                    // 0..1023
    const size_t n0 = (size_t)g * NS;
    const ulonglong2* y2 = (const ulonglong2*)(yat64 + n0 * 16);
    #pragma unroll
    for (int q = 0; q < 8; ++q) {
        const int f = q * 256 + tid;             // 0..2047 (ull2 index)
        const int n = f >> 3;                    // 0..255
        const int b0 = 4 * (f & 7);
        const ulonglong2 pv = y2[f];
        // exact unpack: p = h*2^32 + lo (lo signed); h = (p + 2^31) >> 32
        const int lo0 = (int)(unsigned)pv.x;
        const int hi0 = (int)((pv.x + 0x80000000ULL) >> 32);
        const int lo1 = (int)(unsigned)pv.y;
        const int hi1 = (int)((pv.y + 0x80000000ULL) >> 32);
        T[(b0 + 0) * TPAD + n] = (float)lo0 * FPINV;
        T[(b0 + 1) * TPAD + n] = (float)hi0 * FPINV;
        T[(b0 + 2) * TPAD + n] = (float)lo1 * FPINV;
        T[(b0 + 3) * TPAD + n] = (float)hi1 * FPINV;
    }
    __syncthreads();
    const int b = tid >> 3, j = tid & 7;
    const float* ytb = yt + (size_t)b * NGRID + n0;
    const float* ypb = yp + (size_t)b * NGRID + n0;
    const float* Tb = &T[b * TPAD];
    float c1 = 0.f, c2 = 0.f, c3 = 0.f, st = 0.f, sy = 0.f;
    #pragma unroll
    for (int s = 0; s < NS / 32; ++s) {          // 8 steps
        const int n = 4 * j + 32 * s;
        const float4 a = *(const float4*)(Tb + n);     // ds_read_b128
        const float4 t = *(const float4*)(ytb + n);
        const float4 p = *(const float4*)(ypb + n);
        c1 = fmaf(p.x, a.x, c1); c2 = fmaf(t.x, a.x, c2);
        c3 = fmaf(a.x, a.x, c3); st = fmaf(t.x, t.x, st);
        sy = fmaf(t.x, p.x, sy);
        c1 = fmaf(p.y, a.y, c1); c2 = fmaf(t.y, a.y, c2);
        c3 = fmaf(a.y, a.y, c3); st = fmaf(t.y, t.y, st);
        sy = fmaf(t.y, p.y, sy);
        c1 = fmaf(p.z, a.z, c1); c2 = fmaf(t.z, a.z, c2);
        c3 = fmaf(a.z, a.z, c3); st = fmaf(t.z, t.z, st);
        sy = fmaf(t.z, p.z, sy);
        c1 = fmaf(p.w, a.w, c1); c2 = fmaf(t.w, a.w, c2);
        c3 = fmaf(a.w, a.w, c3); st = fmaf(t.w, t.w, st);
        sy = fmaf(t.w, p.w, sy);
    }
    #pragma unroll
    for (int d = 4; d; d >>= 1) {                // reduce 8 lanes per b
        c1 += __shfl_down(c1, d, 8);
        c2 += __shfl_down(c2, d, 8);
        c3 += __shfl_down(c3, d, 8);
        st += __shfl_down(st, d, 8);
        sy += __shfl_down(sy, d, 8);
    }
    if (j == 0) {
        float* row = p2 + (size_t)g * 160;
        row[0 * 32 + b] = c1;
        row[1 * 32 + b] = c2;
        row[2 * 32 + b] = c3;
        row[3 * 32 + b] = st;
        row[4 * 32 + b] = sy;
    }
}

// ---------------------------------------------------------------------------
// K4a: stage-1 reduce. grid = 32 x 256. Block g sums p2 rows 32g..32g+31.
// ---------------------------------------------------------------------------
__global__ __launch_bounds__(256) void k_finish1(
        const float* __restrict__ p2, float* __restrict__ pr2) {
    const int tid = threadIdx.x, g = blockIdx.x;
    if (tid < 160) {
        float acc = 0.f;
        #pragma unroll
        for (int j = 0; j < 32; ++j) acc += p2[(size_t)(g * 32 + j) * 160 + tid];
        pr2[g * 160 + tid] = acc;
    }
}

// ---------------------------------------------------------------------------
// K4b: stage-2 reduce (32 rows) + closed-form loss. 1 block x 256.
// ---------------------------------------------------------------------------
__global__ __launch_bounds__(256) void k_finish2(
        const float* __restrict__ pr2, float* __restrict__ out) {
    __shared__ float tot[160];
    __shared__ float lb[32];
    const int tid = threadIdx.x;
    if (tid < 160) {
        float acc = 0.f;
        #pragma unroll
        for (int j = 0; j < 32; ++j) acc += pr2[j * 160 + tid];
        tot[tid] = acc;
    }
    __syncthreads();
    if (tid < 32) {
        const float c1 = tot[0 + tid];
        const float c2 = tot[32 + tid];
        const float c3 = tot[64 + tid];
        const float stt = tot[96 + tid];
        const float sty = tot[128 + tid];
        const float a = sty / c1;
        lb[tid] = fmaf(a * a, c3, fmaf(-2.f * a, c2, stt));
    }
    __syncthreads();
    if (tid == 0) {
        float s = 0.f;
        #pragma unroll
        for (int i = 0; i < 32; ++i) s += lb[i];
        out[0] = s * (1.0f / 32.0f);
    }
}

// ===========================================================================
extern "C" void kernel_launch(void* const* d_in, const int* in_sizes, int n_in,
                              void* d_out, int out_size, void* d_ws, size_t ws_size,
                              hipStream_t stream) {
    const float* yp = (const float*)d_in[0];   // y_pred (32, N)
    const float* yt = (const float*)d_in[1];   // y_true (32, N)
    const float* Av = (const float*)d_in[2];   // A_vals (NNZ)
    const int*   Ar = (const int*)d_in[3];     // A_rows (NNZ)
    const int*   Ac = (const int*)d_in[4];     // A_cols (NNZ)
    float* out = (float*)d_out;

    // Workspace: yp_t 33.6MB + yat64 33.6MB + p2 640KB + pr2 20KB ≈ 68 MB
    // (round-0 proved >= 82.5 MB available).
    float* ws    = (float*)d_ws;
    float* yp_t  = ws;                              // N*32 f32
    float* yat_f = yp_t + (size_t)NGRID * 32;       // N*16 u64 (same bytes)
    unsigned long long* yat64 = (unsigned long long*)yat_f;
    float* p2    = yat_f + (size_t)NGRID * 32;      // 1024*160
    float* pr2   = p2 + 1024 * 160;                 // 32*160

    k_prep<<<1024, 256, 0, stream>>>(yp, yp_t, yat_f);
    k_scatter<<<(NNZ_C * 16) / 256, 256, 0, stream>>>(Av, Ar, Ac, yp_t, yat64);
    k_post<<<1024, 256, 0, stream>>>(yat64, yp, yt, p2);
    k_finish1<<<32, 256, 0, stream>>>(p2, pr2);
    k_finish2<<<1, 256, 0, stream>>>(pr2, out);
}